// Round 13
// baseline (307.426 us; speedup 1.0000x reference)
//
#include <hip/hip_runtime.h>
#include <math.h>
#include <stdint.h>

using u16 = unsigned short;
using u32 = uint32_t;

// Problem constants
constexpr int cB = 2;
constexpr int cQ = 1024;
constexpr int cM = 1024;
constexpr int cU = 1024;
constexpr int cH = 16;
constexpr int cD = 64;
constexpr int cK = 2048;    // KLEN
constexpr int cRROWS = 2112; // R fragment buffer rows (covers OOB window to 2111)
constexpr int cWPAD = 2176;  // w_all row stride

typedef __bf16 v8bf  __attribute__((ext_vector_type(8)));
typedef float  v16f  __attribute__((ext_vector_type(16)));

#define MFMA32(a, b, c) __builtin_amdgcn_mfma_f32_32x32x16_bf16((a), (b), (c), 0, 0, 0)

__device__ __forceinline__ u16 f2bf(float f) {   // RTN float->bf16 bits
    u32 u = __float_as_uint(f);
    u += 0x7fffu + ((u >> 16) & 1u);
    return (u16)(u >> 16);
}
__device__ __forceinline__ float bf2f(u16 s) {
    return __uint_as_float(((u32)s) << 16);
}

union Frag { v8bf v; u16 s[8]; uint2 d2[2]; uint4 q4; };

typedef const u32 __attribute__((address_space(1)))* gp1;
typedef u32 __attribute__((address_space(3)))* lp3;

// ---------------------------------------------------------------------------
// ROUND 20: convert_acts + convert_wT FUSED into one launch (bid-partitioned;
// both BW-bound and independent -> the 6 µs weight convert rides under the
// 11 µs activation convert instead of serializing after it). Math identical.
// bid < 8192: activation hi/lo planes. bid >= 8192: weight transpose hi/lo.
// ---------------------------------------------------------------------------
__global__ __launch_bounds__(256)
void convert_fused(const float* __restrict__ inputs, const float* __restrict__ memories,
                   const float* __restrict__ relatives,
                   u16* __restrict__ fullH, u16* __restrict__ fullL,
                   u16* __restrict__ relH,  u16* __restrict__ relL,
                   const float* __restrict__ Wq, const float* __restrict__ Wkv,
                   const float* __restrict__ Wr, const float* __restrict__ Wo,
                   u16* __restrict__ WqTH, u16* __restrict__ WqTL,
                   u16* __restrict__ WkvTH, u16* __restrict__ WkvTL,
                   u16* __restrict__ WrTH, u16* __restrict__ WrTL,
                   u16* __restrict__ WoTH, u16* __restrict__ WoTL)
{
    __shared__ float tl[64][65];
    const int t = threadIdx.x;

    if (blockIdx.x < 8192) {
        // ---- activation path (was convert_acts) ----
        const int idx = blockIdx.x * 256 + t;
        const float* src;
        u16 *dh, *dl;
        int q;
        if (idx < (1 << 20)) {                            // full = concat(mem, inp)
            q = idx;
            const int row = q >> 8;
            const int col = (q & 255) * 4;
            const int b = row >> 11, l = row & (cK - 1);
            src = (l < cM) ? (memories + ((size_t)b * cM + l) * cU + col)
                           : (inputs   + ((size_t)b * cQ + (l - cM)) * cU + col);
            dh = fullH; dl = fullL;
        } else {
            q = idx - (1 << 20);
            src = relatives + (size_t)q * 4;
            dh = relH; dl = relL;
        }
        const float4 f = *(const float4*)src;
        const float xs[4] = {f.x, f.y, f.z, f.w};
        u16 hi[4], lo[4];
        #pragma unroll
        for (int j = 0; j < 4; ++j) {
            hi[j] = f2bf(xs[j]);
            lo[j] = f2bf(xs[j] - bf2f(hi[j]));
        }
        uint2 ph, pl;
        ph.x = hi[0] | ((u32)hi[1] << 16); ph.y = hi[2] | ((u32)hi[3] << 16);
        pl.x = lo[0] | ((u32)lo[1] << 16); pl.y = lo[2] | ((u32)lo[3] << 16);
        *(uint2*)(dh + (size_t)q * 4) = ph;
        *(uint2*)(dl + (size_t)q * 4) = pl;
        return;
    }

    // ---- weight transpose path (was convert_wT) ----
    int bid = blockIdx.x - 8192;
    const float* src; u16 *dh, *dl; int N, tK, tN;
    if (bid < 256)       { src = Wq;  dh = WqTH;  dl = WqTL;  N = 1024; tK = bid >> 4; tN = bid & 15; }
    else if (bid < 768)  { bid -= 256; src = Wkv; dh = WkvTH; dl = WkvTL; N = 2048; tK = bid >> 5; tN = bid & 31; }
    else if (bid < 1024) { bid -= 768; src = Wr;  dh = WrTH;  dl = WrTL;  N = 1024; tK = bid >> 4; tN = bid & 15; }
    else                 { bid -= 1024; src = Wo; dh = WoTH;  dl = WoTL;  N = 1024; tK = bid >> 4; tN = bid & 15; }
    const int k0 = tK * 64, n0 = tN * 64;

    #pragma unroll
    for (int i = 0; i < 16; ++i) {
        const int idx = i * 256 + t;
        const int r = idx >> 6, c = idx & 63;
        tl[r][c] = src[(size_t)(k0 + r) * N + n0 + c];
    }
    __syncthreads();
    #pragma unroll
    for (int i = 0; i < 16; ++i) {
        const int idx = i * 256 + t;
        const int rn = idx >> 6, ck = idx & 63;
        const float x = tl[ck][rn];
        const u16 hi = f2bf(x);
        const u16 lo = f2bf(x - bf2f(hi));
        const size_t o = (size_t)(n0 + rn) * 1024 + k0 + ck;
        dh[o] = hi; dl[o] = lo;
    }
}

// ---------------------------------------------------------------------------
// bf16 MFMA GEMM — round-1 proven structure (2-phase dbuf, counted vmcnt(8)).
// gemm_mfma<32> = main fused launch; gemm_mfma<8> = split-K x4 out-projection.
// ---------------------------------------------------------------------------
template <int TNT>
__global__ __launch_bounds__(256)
void gemm_mfma(const u16* __restrict__ fullH, const u16* __restrict__ fullL,
               const u16* __restrict__ relH,  const u16* __restrict__ relL,
               const u16* __restrict__ WqTH,  const u16* __restrict__ WqTL,
               const u16* __restrict__ WkvTH, const u16* __restrict__ WkvTL,
               const u16* __restrict__ WrTH,  const u16* __restrict__ WrTL,
               const u16* __restrict__ atH,   const u16* __restrict__ atL,
               const u16* __restrict__ WoTH,  const u16* __restrict__ WoTL,
               const float* __restrict__ bias_c,
               float* __restrict__ qc, u16* __restrict__ kb16, u16* __restrict__ vb16,
               u16* __restrict__ rb16, float* __restrict__ outp)
{
    extern __shared__ char lds[];   // main: 49152 B (2 x 24K); mode4: 65536 B (2 x 32K)
    constexpr int BSTR = (TNT == 8) ? 32768 : 24576;     // per-buffer stride

    int bid = blockIdx.x;
    int mode, m0, n0, arow0, npass;
    int kt0 = 0;                     // starting K-tile (split-K offset)
    const u16 *aH, *aL, *bH, *bL;
    if (TNT == 8) {
        // split-K x4: 512 blocks; sk = K-slice, local = (m,n) tile
        const int sk = bid >> 7;
        const int local = bid & 127;
        const int x = local & 7, g = local >> 3;         // g in [0,16)
        m0 = ((x >> 1) * 4 + (g >> 2)) * 128;
        n0 = ((x & 1) * 4 + (g & 3)) * 128;
        mode = 4; aH = atH; aL = atL; bH = WoTH; bL = WoTL; arow0 = m0; npass = 3;
        kt0 = sk * 8;
        outp += (size_t)sk * (2048u * 1024u);            // fp32 partial buffer
    } else if (bid < 128) {
        const int x = bid & 7, g = bid >> 3;             // g in [0,16)
        m0 = ((x >> 1) * 4 + (g >> 2)) * 128;
        n0 = ((x & 1) * 4 + (g & 3)) * 128;
        mode = 1; aH = fullH; aL = fullL; bH = WqTH; bL = WqTL;
        arow0 = (m0 >> 10) * cK + cM + (m0 & (cQ - 1)); npass = 2;
    } else if (bid < 640) {
        const int local = bid - 128;
        const int x = local & 7, g = local >> 3;         // g in [0,64)
        m0 = ((x >> 1) * 8 + (g >> 3)) * 128;
        n0 = ((x & 1) * 8 + (g & 7)) * 128;
        mode = 2; aH = fullH; aL = fullL; bH = WkvTH; bL = WkvTL; arow0 = m0;
        npass = (n0 >= cU) ? 1 : 2;
    } else {
        const int local = bid - 640;
        const int x = local & 7, g = local >> 3;         // g in [0,32)
        m0 = ((x >> 1) * 8 + (g >> 2)) * 128;
        n0 = ((x & 1) * 4 + (g & 3)) * 128;
        mode = 3; aH = relH; aL = relL; bH = WrTH; bL = WrTL; arow0 = m0; npass = 2;
    }

    const int t = threadIdx.x, w = t >> 6, lane = t & 63;

    const int rl = lane >> 2;
    const int cl = (lane & 3) ^ ((lane >> 3) & 3);  // XOR-swizzled chunk
    const u16* src;
    if (w == 0)      src = aH + (size_t)(arow0 + rl) * 1024 + cl * 8;
    else if (w == 1) src = aL + (size_t)(arow0 + rl) * 1024 + cl * 8;
    else if (w == 2) src = bH + (size_t)(n0 + rl) * 1024 + cl * 8;
    else             src = bL + (size_t)(n0 + rl) * 1024 + cl * 8;
    src += (size_t)kt0 * 32;                             // K-slice offset
    const int planeOff = w * 8192;
    const bool doStage = (w == 0) || (w == 2) || (w == 1 && npass >= 2) || (w == 3 && npass >= 3);

    // stage K-tile k (relative to kt0) into buffer buf
    auto stage = [&](int k, int buf) {
        if (doStage) {
            const u16* s = src + (size_t)k * 32;
            char* dst = lds + buf * BSTR + planeOff;
            #pragma unroll
            for (int g2 = 0; g2 < 8; ++g2)
                __builtin_amdgcn_global_load_lds((gp1)(s + (size_t)g2 * 16 * 1024),
                                                 (lp3)(dst + g2 * 1024), 16, 0, 0);
        }
    };

    const int l31 = lane & 31, hk = lane >> 5;
    const int fsw = (l31 >> 1) & 3;
    const int koff[2] = { ((hk ^ fsw) << 4), (((2 + hk) ^ fsw) << 4) };
    const int mwb = (w >> 1) * 4096 + l31 * 64;
    const int nwb = (w & 1) * 4096 + l31 * 64;

    v16f acc[2][2];
    #pragma unroll
    for (int i = 0; i < 16; ++i) { acc[0][0][i] = 0.f; acc[0][1][i] = 0.f; acc[1][0][i] = 0.f; acc[1][1][i] = 0.f; }

    // ---- prologue: tiles 0 and 1 in flight; wait only for tile 0 ----
    stage(0, 0);
    stage(1, 1);
    asm volatile("s_waitcnt vmcnt(8)" ::: "memory");
    __builtin_amdgcn_s_barrier();
    asm volatile("" ::: "memory");

    for (int kit = 0; kit < TNT; ++kit) {
        const char* ldsb = lds + ((kit & 1) ? BSTR : 0);

        #pragma unroll
        for (int s = 0; s < 2; ++s) {
            const int ko = koff[s];
            const v8bf ah0 = *(const v8bf*)(ldsb + mwb + ko);
            const v8bf ah1 = *(const v8bf*)(ldsb + mwb + 2048 + ko);
            const v8bf bh0 = *(const v8bf*)(ldsb + 16384 + nwb + ko);
            const v8bf bh1 = *(const v8bf*)(ldsb + 16384 + nwb + 2048 + ko);
            acc[0][0] = MFMA32(ah0, bh0, acc[0][0]);
            acc[0][1] = MFMA32(ah0, bh1, acc[0][1]);
            acc[1][0] = MFMA32(ah1, bh0, acc[1][0]);
            acc[1][1] = MFMA32(ah1, bh1, acc[1][1]);
            if (npass >= 2) {
                const v8bf al0 = *(const v8bf*)(ldsb + 8192 + mwb + ko);
                const v8bf al1 = *(const v8bf*)(ldsb + 8192 + mwb + 2048 + ko);
                acc[0][0] = MFMA32(al0, bh0, acc[0][0]);
                acc[0][1] = MFMA32(al0, bh1, acc[0][1]);
                acc[1][0] = MFMA32(al1, bh0, acc[1][0]);
                acc[1][1] = MFMA32(al1, bh1, acc[1][1]);
            }
            if (npass >= 3) {
                const v8bf bl0 = *(const v8bf*)(ldsb + 24576 + nwb + ko);
                const v8bf bl1 = *(const v8bf*)(ldsb + 24576 + nwb + 2048 + ko);
                acc[0][0] = MFMA32(ah0, bl0, acc[0][0]);
                acc[0][1] = MFMA32(ah0, bl1, acc[0][1]);
                acc[1][0] = MFMA32(ah1, bl0, acc[1][0]);
                acc[1][1] = MFMA32(ah1, bl1, acc[1][1]);
            }
        }

        if (kit == TNT - 1) break;

        // A: all waves done reading buf[kit&1]
        asm volatile("" ::: "memory");
        __builtin_amdgcn_s_barrier();
        asm volatile("" ::: "memory");

        if (kit <= TNT - 3) {
            stage(kit + 2, kit & 1);                       // overwrite freed buffer
            asm volatile("s_waitcnt vmcnt(8)" ::: "memory"); // tile kit+1 landed
        } else {
            asm volatile("s_waitcnt vmcnt(0)" ::: "memory"); // drain last tile
        }

        // B: publish buf[(kit+1)&1]
        __builtin_amdgcn_s_barrier();
        asm volatile("" ::: "memory");
    }

    #pragma unroll
    for (int mi = 0; mi < 2; ++mi)
    #pragma unroll
    for (int ni = 0; ni < 2; ++ni) {
        const int n = n0 + (w & 1) * 64 + ni * 32 + l31;
        #pragma unroll
        for (int e = 0; e < 16; ++e) {
            const int m = m0 + (w >> 1) * 64 + mi * 32 + (e & 3) + 8 * (e >> 2) + 4 * hk;
            const float v = acc[mi][ni][e];
            if (mode == 1) {
                const int b = m >> 10, q = m & (cQ - 1);
                const int h = n >> 6, d = n & 63;
                qc[(((size_t)(b * cH + h)) * cQ + q) * cD + d] = v + bias_c[n];
            } else if (mode == 2) {
                const int b = m >> 11, l = m & (cK - 1);
                const int nn = n & (cU - 1);
                const int h = nn >> 6, d = nn & 63;
                if (n >= cU)   // V fragment-linear
                    vb16[(size_t)(b * cH + h) * cK * cD + ((l >> 6) * 4096)
                         + (((l >> 4) & 3) * 1024) + (((l >> 3) & 1) * 512)
                         + d * 8 + (l & 7)] = f2bf(v);
                else           // K fragment-linear
                    kb16[(size_t)(b * cH + h) * cK * cD + ((l >> 6) * 4096)
                         + ((d >> 4) * 1024) + (((d >> 3) & 1) * 512)
                         + ((l & 63) * 8) + (d & 7)] = f2bf(v);
            } else if (mode == 3) {
                const int b = m >> 11, l = m & (cK - 1);
                const int h = n >> 6, d = n & 63;
                rb16[(size_t)(b * cH + h) * cRROWS * cD + ((l >> 5) * 2048)
                     + ((d >> 4) * 512) + (((d >> 3) & 1) * 256)
                     + ((l & 31) * 8) + (d & 7)] = f2bf(v);
            } else {
                outp[(size_t)m * cU + n] = v;              // fp32 partial
            }
        }
    }
}

// ---------------------------------------------------------------------------
// add4: out = p0 + p1 + p2 + p3 (split-K reduction for the out-projection)
// ---------------------------------------------------------------------------
__global__ __launch_bounds__(256)
void add4(const float* __restrict__ part, float* __restrict__ out)
{
    const size_t base = ((size_t)blockIdx.x * 256 + threadIdx.x) * 4;
    constexpr size_t S = 2048u * 1024u;
    const float4 a = *(const float4*)(part + base);
    const float4 b = *(const float4*)(part + S + base);
    const float4 c = *(const float4*)(part + 2 * S + base);
    const float4 d = *(const float4*)(part + 3 * S + base);
    float4 r;
    r.x = (a.x + b.x) + (c.x + d.x);
    r.y = (a.y + b.y) + (c.y + d.y);
    r.z = (a.z + b.z) + (c.z + d.z);
    r.w = (a.w + b.w) + (c.w + d.w);
    *(float4*)(out + base) = r;
}

// ---------------------------------------------------------------------------
// wvec: w_all[bh][win] = sum_d r[bh][win][d] * (bias_r - bias_c)[h][d]
// ---------------------------------------------------------------------------
__global__ __launch_bounds__(256)
void wvec_kernel(const u16* __restrict__ rb16, const float* __restrict__ bias_c,
                 const float* __restrict__ bias_r, float* __restrict__ w_all)
{
    const int t = threadIdx.x, w = t >> 6, lane = t & 63;
    #pragma unroll 4
    for (int it = 0; it < 16; ++it) {
        const int row = blockIdx.x * 64 + it * 4 + w;    // 65536 rows
        const int bh = row >> 11, g = row & (cK - 1);
        const int h = bh & (cH - 1);
        const float d = bias_r[h * 64 + lane] - bias_c[h * 64 + lane];
        const size_t idx = (size_t)bh * cRROWS * cD + ((g >> 5) * 2048)
                         + ((lane >> 4) * 512) + (((lane >> 3) & 1) * 256)
                         + ((g & 31) * 8) + (lane & 7);
        float v = bf2f(rb16[idx]) * d;
        #pragma unroll
        for (int off = 1; off <= 32; off <<= 1)
            v += __shfl_xor(v, off);
        if (lane == 0) w_all[(size_t)bh * cWPAD + g] = v;
    }
}

// ---------------------------------------------------------------------------
// MFMA flash attention — ROUND-7 PROVEN KERNEL, VERBATIM (best measured:
// 88.6 µs). r8-r12 post-mortems: global-direct K/R (108), counted-drain
// barriers (90.2, neutral), split-K x4 (93.1, fixed-cost regression) all
// lose to this staged split-x2 form; its floor is the VALU softmax chain
// at 3-blocks/CU residency — structural, not fixable by barrier/occupancy
// tweaks within this layout.
// ---------------------------------------------------------------------------
__global__ __launch_bounds__(256, 4)
void flash_mfma(const float* __restrict__ qcg, const u16* __restrict__ kbg,
                const u16* __restrict__ vbg, const u16* __restrict__ rbg,
                const float* __restrict__ w_all,
                float* __restrict__ oPart, float* __restrict__ lPart)
{
    __shared__ u16 KhL[4096];        // fragment-linear K chunk (8 KB)
    __shared__ u16 RhL[8192];        // fragment-linear R window (16 KB)
    __shared__ u16 SrelT[128][68];   // [window][q-row] bf16 (wv folded)
    __shared__ u16 Ph[64][68];       // [q-row][key] bf16
    __shared__ float lrow[2][64];

    const int bid = blockIdx.x;
    const int hb = bid & 31;
    const int inner = bid >> 5;
    const int qb = inner & 15;
    const int sp = inner >> 4;         // split 0/1
    const int h = hb >> 1, b = hb & 1;
    const int bh = b * cH + h;
    const int q0 = qb * 64;

    const u16* kgf = kbg + (size_t)bh * cK * cD;
    const u16* vgf = vbg + (size_t)bh * cK * cD;
    const u16* rgf = rbg + (size_t)bh * cRROWS * cD;
    const float* qg = qcg + (size_t)bh * cQ * cD;
    const float* wg = w_all + (size_t)bh * cWPAD;

    const int t = threadIdx.x, w = t >> 6, lane = t & 63;
    const int l31 = lane & 31, hk = lane >> 5;
    const int rloc0 = (w >> 1) * 32;
    const int c0 = (w & 1) * 32;
    const int wc0 = (w & 1) * 64 + l31;

    Frag qch[4];
    {
        const float* qrow = qg + (size_t)(q0 + rloc0 + l31) * cD;
        #pragma unroll
        for (int kc = 0; kc < 4; ++kc) {
            const int dh0 = kc * 16 + hk * 8;
            const float4 f0 = *(const float4*)(qrow + dh0);
            const float4 f1 = *(const float4*)(qrow + dh0 + 4);
            const float xs[8] = {f0.x, f0.y, f0.z, f0.w, f1.x, f1.y, f1.z, f1.w};
            #pragma unroll
            for (int j = 0; j < 8; ++j) qch[kc].s[j] = f2bf(xs[j]);
        }
    }

    v16f aO;
    float lpart[16];
    #pragma unroll
    for (int i = 0; i < 16; ++i) { aO[i] = 0.f; lpart[i] = 0.f; }

    const int nch = 17 + qb;
    int j0 = sp * 64;

    auto dma = [&](int jn, int relbn) {
        #pragma unroll
        for (int i = 0; i < 6; ++i) {
            const int id = w * 6 + i;
            if (id < 8) {
                const u16* s = kgf + (size_t)(jn >> 6) * 4096 + id * 512;
                __builtin_amdgcn_global_load_lds((gp1)(s + lane * 8),
                                                 (lp3)((char*)KhL + id * 1024), 16, 0, 0);
            } else {
                const int jj = id - 8;
                const u16* s = rgf + ((size_t)(relbn >> 5) + (jj >> 2)) * 2048 + (jj & 3) * 512;
                __builtin_amdgcn_global_load_lds((gp1)(s + lane * 8),
                                                 (lp3)((char*)RhL + jj * 1024), 16, 0, 0);
            }
        }
    };

    dma(j0, j0 - q0 + 960);
    __syncthreads();

    for (int c = sp; c < nch; c += 2) {
        const int relbase = j0 - q0 + 960;

        Frag vf[4];
        #pragma unroll
        for (int kc = 0; kc < 4; ++kc)
            vf[kc].q4 = *(const uint4*)(vgf + (size_t)(j0 >> 6) * 4096
                                        + kc * 1024 + hk * 512 + (c0 + l31) * 8);
        const float wv0 = wg[relbase + wc0];
        const float wv1 = wg[relbase + wc0 + 32];

        v16f actx;
        #pragma unroll
        for (int i = 0; i < 16; ++i) actx[i] = 0.f;
        #pragma unroll
        for (int kc = 0; kc < 4; ++kc) {
            Frag kf;
            kf.q4 = *(const uint4*)(KhL + kc * 1024 + hk * 512 + (c0 + l31) * 8);
            actx = MFMA32(qch[kc].v, kf.v, actx);
        }

        #pragma unroll
        for (int half = 0; half < 2; ++half) {
            v16f ar;
            #pragma unroll
            for (int i = 0; i < 16; ++i) ar[i] = 0.f;
            const int lg = (w & 1) * 2 + half;
            #pragma unroll
            for (int kc = 0; kc < 4; ++kc) {
                Frag rf;
                rf.q4 = *(const uint4*)(RhL + lg * 2048 + kc * 512 + hk * 256 + l31 * 8);
                ar = MFMA32(qch[kc].v, rf.v, ar);
            }
            const float wvh = half ? wv1 : wv0;
            const int wch = wc0 + half * 32;
            #pragma unroll
            for (int g = 0; g < 4; ++g) {
                const int rb_ = rloc0 + 8 * g + 4 * hk;
                u16 p[4];
                #pragma unroll
                for (int e = 0; e < 4; ++e) p[e] = f2bf(ar[4 * g + e] + wvh);
                *(uint2*)&SrelT[wch][rb_] = make_uint2(p[0] | ((u32)p[1] << 16),
                                                       p[2] | ((u32)p[3] << 16));
            }
        }
        __syncthreads();   // B: SrelT visible; KhL/RhL fully consumed

        const int jn = (c + 2 < nch) ? j0 + 128 : j0;
        dma(jn, jn - q0 + 960);

        const int jl = c0 + l31;
        const int limit = cM + q0 - j0;
        #pragma unroll
        for (int g = 0; g < 4; ++g)
        #pragma unroll
        for (int e = 0; e < 4; ++e) {
            const int reg  = 4 * g + e;
            const int rloc = rloc0 + e + 8 * g + 4 * hk;
            const int widx = jl - rloc + 63;            // [0,126]
            const float srel = bf2f(SrelT[widx][rloc]);
            const float s = (actx[reg] + srel) * 0.125f - 10.f;
            const float p = (jl > limit + rloc) ? 0.f : __expf(s);
            lpart[reg] += p;
            Ph[rloc][jl] = f2bf(p);
        }
        __syncthreads();   // C: Ph visible; DMA drained

        #pragma unroll
        for (int kc = 0; kc < 4; ++kc) {
            const int kb0 = kc * 16 + hk * 8;
            Frag pf;
            pf.d2[0] = *(const uint2*)&Ph[rloc0 + l31][kb0];
            pf.d2[1] = *(const uint2*)&Ph[rloc0 + l31][kb0 + 4];
            aO = MFMA32(pf.v, vf[kc].v, aO);
        }
        j0 += 128;
    }

    #pragma unroll
    for (int off = 1; off <= 16; off <<= 1)
        #pragma unroll
        for (int i = 0; i < 16; ++i) lpart[i] += __shfl_xor(lpart[i], off);
    if (l31 == 0) {
        #pragma unroll
        for (int g = 0; g < 4; ++g)
        #pragma unroll
        for (int e = 0; e < 4; ++e)
            lrow[w & 1][rloc0 + e + 8 * g + 4 * hk] = lpart[4 * g + e];
    }
    __syncthreads();

    float* ob = oPart + (size_t)sp * ((size_t)cB * cQ * cU);
    #pragma unroll
    for (int g = 0; g < 4; ++g)
    #pragma unroll
    for (int e = 0; e < 4; ++e) {
        const int reg  = 4 * g + e;
        const int rloc = rloc0 + e + 8 * g + 4 * hk;
        ob[((size_t)(b * cQ + q0 + rloc)) * cU + h * 64 + c0 + l31] = aO[reg];
    }
    if (t < 64)
        lPart[(size_t)sp * (cB * cH * cQ) + (size_t)bh * cQ + q0 + t] = lrow[0][t] + lrow[1][t];
}

// ---------------------------------------------------------------------------
// combine: o = (o0+o1)/(l0+l1), write bf16 hi/lo for the out-GEMM.
// ---------------------------------------------------------------------------
__global__ __launch_bounds__(256)
void combine(const float* __restrict__ oPart, const float* __restrict__ lPart,
             u16* __restrict__ atH, u16* __restrict__ atL)
{
    const int idx = blockIdx.x * 256 + threadIdx.x;
    const size_t base = (size_t)idx * 4;
    const int b = (int)(base >> 20);
    const int rem = (int)(base & ((1u << 20) - 1));
    const int q = rem >> 10;
    const int u = rem & 1023;
    const int h = u >> 6;
    const float4 o0 = *(const float4*)(oPart + base);
    const float4 o1 = *(const float4*)(oPart + (size_t)cB * cQ * cU + base);
    const int li = (b * cH + h) * cQ + q;
    const float l = lPart[li] + lPart[cB * cH * cQ + li];
    const float inv = 1.f / l;
    const float vals[4] = {(o0.x + o1.x) * inv, (o0.y + o1.y) * inv,
                           (o0.z + o1.z) * inv, (o0.w + o1.w) * inv};
    u16 hi[4], lo[4];
    #pragma unroll
    for (int j = 0; j < 4; ++j) {
        hi[j] = f2bf(vals[j]);
        lo[j] = f2bf(vals[j] - bf2f(hi[j]));
    }
    uint2 ph, pl;
    ph.x = hi[0] | ((u32)hi[1] << 16); ph.y = hi[2] | ((u32)hi[3] << 16);
    pl.x = lo[0] | ((u32)lo[1] << 16); pl.y = lo[2] | ((u32)lo[3] << 16);
    *(uint2*)(atH + base) = ph;
    *(uint2*)(atL + base) = pl;
}

// ---------------------------------------------------------------------------
extern "C" void kernel_launch(void* const* d_in, const int* in_sizes, int n_in,
                              void* d_out, int out_size, void* d_ws, size_t ws_size,
                              hipStream_t stream)
{
    const float* inputs    = (const float*)d_in[0];
    const float* relatives = (const float*)d_in[1];
    const float* memories  = (const float*)d_in[2];
    const float* bias_c    = (const float*)d_in[3];
    const float* bias_r    = (const float*)d_in[4];
    const float* Wq        = (const float*)d_in[5];
    const float* Wkv       = (const float*)d_in[6];
    const float* Wr        = (const float*)d_in[7];
    const float* Wo        = (const float*)d_in[8];
    float* out = (float*)d_out;

    char* p = (char*)d_ws;
    auto alloc = [&](size_t bytes) { char* r = p; p += bytes; return r; };
    u16* fullH = (u16*)alloc(8u << 20);
    u16* fullL = (u16*)alloc(8u << 20);
    u16* relH  = (u16*)alloc(8u << 20);   // oPart aliases relH+relL after proj
    u16* relL  = (u16*)alloc(8u << 20);
    u16* WqTH  = (u16*)alloc(2u << 20);
    u16* WqTL  = (u16*)alloc(2u << 20);
    u16* WkvTH = (u16*)alloc(4u << 20);
    u16* WkvTL = (u16*)alloc(4u << 20);
    u16* WrTH  = (u16*)alloc(2u << 20);
    u16* WrTL  = (u16*)alloc(2u << 20);
    u16* WoTH  = (u16*)alloc(2u << 20);
    u16* WoTL  = (u16*)alloc(2u << 20);
    float* qc  = (float*)alloc(8u << 20);
    u16* kb16  = (u16*)alloc(8u << 20);
    u16* vb16  = (u16*)alloc(8u << 20);
    u16* rb16  = (u16*)alloc(9u << 20);   // 32 bh x 2112 rows x 64 (fragment-linear)
    float* w_all = (float*)alloc(32u * cWPAD * 4u);
    float* lPart = (float*)alloc(2u * cB * cH * cQ * 4u);
    u16* atH   = (u16*)alloc(4u << 20);
    u16* atL   = (u16*)alloc(4u << 20);
    float* oPart = (float*)relH;          // 16 MB, reuses rel planes
    float* part4 = (float*)d_ws;          // 32 MB overlay (fullH..relL), free
                                          // after combine; holds split-K partials

    convert_fused<<<9472, 256, 0, stream>>>(inputs, memories, relatives,
                                            fullH, fullL, relH, relL,
                                            Wq, Wkv, Wr, Wo,
                                            WqTH, WqTL, WkvTH, WkvTL,
                                            WrTH, WrTL, WoTH, WoTL);
    gemm_mfma<32><<<896, 256, 49152, stream>>>(fullH, fullL, relH, relL,
                                               WqTH, WqTL, WkvTH, WkvTL, WrTH, WrTL,
                                               atH, atL, WoTH, WoTL, bias_c,
                                               qc, kb16, vb16, rb16, out);
    wvec_kernel<<<1024, 256, 0, stream>>>(rb16, bias_c, bias_r, w_all);
    flash_mfma<<<1024, 256, 0, stream>>>(qc, kb16, vb16, rb16, w_all, oPart, lPart);
    combine<<<2048, 256, 0, stream>>>(oPart, lPart, atH, atL);
    gemm_mfma<8><<<512, 256, 65536, stream>>>(fullH, fullL, relH, relL,
                                              WqTH, WqTL, WkvTH, WkvTL, WrTH, WrTL,
                                              atH, atL, WoTH, WoTL, bias_c,
                                              qc, kb16, vb16, rb16, part4);
    add4<<<2048, 256, 0, stream>>>(part4, out);
}

// Round 14
// 295.837 us; speedup vs baseline: 1.0392x; 1.0392x over previous
//
#include <hip/hip_runtime.h>
#include <math.h>
#include <stdint.h>

using u16 = unsigned short;
using u32 = uint32_t;

// Problem constants
constexpr int cB = 2;
constexpr int cQ = 1024;
constexpr int cM = 1024;
constexpr int cU = 1024;
constexpr int cH = 16;
constexpr int cD = 64;
constexpr int cK = 2048;    // KLEN
constexpr int cRROWS = 2112; // R fragment buffer rows (covers OOB window to 2111)
constexpr int cWPAD = 2176;  // w_all row stride

typedef __bf16 v8bf  __attribute__((ext_vector_type(8)));
typedef float  v16f  __attribute__((ext_vector_type(16)));

#define MFMA32(a, b, c) __builtin_amdgcn_mfma_f32_32x32x16_bf16((a), (b), (c), 0, 0, 0)

__device__ __forceinline__ u16 f2bf(float f) {   // RTN float->bf16 bits (integer path)
    u32 u = __float_as_uint(f);
    u += 0x7fffu + ((u >> 16) & 1u);
    return (u16)(u >> 16);
}
// ROUND 21: hardware RTNE convert — native __bf16 cast lets ISel emit
// v_cvt_pk_bf16_f32 (1 op / 2 converts) instead of the 3-op integer RTNE
// sequence. Bit-identical to f2bf for all finite inputs (both RTNE).
// Used ONLY in flash_mfma's hot VALU paths (m240: let the compiler emit
// cvt_pk, don't hand-write it).
__device__ __forceinline__ u16 f2bf_hw(float f) {
    __bf16 b = (__bf16)f;
    return __builtin_bit_cast(u16, b);
}
__device__ __forceinline__ float bf2f(u16 s) {
    return __uint_as_float(((u32)s) << 16);
}

union Frag { v8bf v; u16 s[8]; uint2 d2[2]; uint4 q4; };

typedef const u32 __attribute__((address_space(1)))* gp1;
typedef u32 __attribute__((address_space(3)))* lp3;

// ---------------------------------------------------------------------------
// convert_acts + convert_wT fused (bid-partitioned; both BW-bound).
// ---------------------------------------------------------------------------
__global__ __launch_bounds__(256)
void convert_fused(const float* __restrict__ inputs, const float* __restrict__ memories,
                   const float* __restrict__ relatives,
                   u16* __restrict__ fullH, u16* __restrict__ fullL,
                   u16* __restrict__ relH,  u16* __restrict__ relL,
                   const float* __restrict__ Wq, const float* __restrict__ Wkv,
                   const float* __restrict__ Wr, const float* __restrict__ Wo,
                   u16* __restrict__ WqTH, u16* __restrict__ WqTL,
                   u16* __restrict__ WkvTH, u16* __restrict__ WkvTL,
                   u16* __restrict__ WrTH, u16* __restrict__ WrTL,
                   u16* __restrict__ WoTH, u16* __restrict__ WoTL)
{
    __shared__ float tl[64][65];
    const int t = threadIdx.x;

    if (blockIdx.x < 8192) {
        // ---- activation path ----
        const int idx = blockIdx.x * 256 + t;
        const float* src;
        u16 *dh, *dl;
        int q;
        if (idx < (1 << 20)) {                            // full = concat(mem, inp)
            q = idx;
            const int row = q >> 8;
            const int col = (q & 255) * 4;
            const int b = row >> 11, l = row & (cK - 1);
            src = (l < cM) ? (memories + ((size_t)b * cM + l) * cU + col)
                           : (inputs   + ((size_t)b * cQ + (l - cM)) * cU + col);
            dh = fullH; dl = fullL;
        } else {
            q = idx - (1 << 20);
            src = relatives + (size_t)q * 4;
            dh = relH; dl = relL;
        }
        const float4 f = *(const float4*)src;
        const float xs[4] = {f.x, f.y, f.z, f.w};
        u16 hi[4], lo[4];
        #pragma unroll
        for (int j = 0; j < 4; ++j) {
            hi[j] = f2bf(xs[j]);
            lo[j] = f2bf(xs[j] - bf2f(hi[j]));
        }
        uint2 ph, pl;
        ph.x = hi[0] | ((u32)hi[1] << 16); ph.y = hi[2] | ((u32)hi[3] << 16);
        pl.x = lo[0] | ((u32)lo[1] << 16); pl.y = lo[2] | ((u32)lo[3] << 16);
        *(uint2*)(dh + (size_t)q * 4) = ph;
        *(uint2*)(dl + (size_t)q * 4) = pl;
        return;
    }

    // ---- weight transpose path ----
    int bid = blockIdx.x - 8192;
    const float* src; u16 *dh, *dl; int N, tK, tN;
    if (bid < 256)       { src = Wq;  dh = WqTH;  dl = WqTL;  N = 1024; tK = bid >> 4; tN = bid & 15; }
    else if (bid < 768)  { bid -= 256; src = Wkv; dh = WkvTH; dl = WkvTL; N = 2048; tK = bid >> 5; tN = bid & 31; }
    else if (bid < 1024) { bid -= 768; src = Wr;  dh = WrTH;  dl = WrTL;  N = 1024; tK = bid >> 4; tN = bid & 15; }
    else                 { bid -= 1024; src = Wo; dh = WoTH;  dl = WoTL;  N = 1024; tK = bid >> 4; tN = bid & 15; }
    const int k0 = tK * 64, n0 = tN * 64;

    #pragma unroll
    for (int i = 0; i < 16; ++i) {
        const int idx = i * 256 + t;
        const int r = idx >> 6, c = idx & 63;
        tl[r][c] = src[(size_t)(k0 + r) * N + n0 + c];
    }
    __syncthreads();
    #pragma unroll
    for (int i = 0; i < 16; ++i) {
        const int idx = i * 256 + t;
        const int rn = idx >> 6, ck = idx & 63;
        const float x = tl[ck][rn];
        const u16 hi = f2bf(x);
        const u16 lo = f2bf(x - bf2f(hi));
        const size_t o = (size_t)(n0 + rn) * 1024 + k0 + ck;
        dh[o] = hi; dl[o] = lo;
    }
}

// ---------------------------------------------------------------------------
// bf16 MFMA GEMM — round-1 proven structure (2-phase dbuf, counted vmcnt(8)).
// gemm_mfma<32> = main fused launch; gemm_mfma<8> = split-K x4 out-projection.
// ---------------------------------------------------------------------------
template <int TNT>
__global__ __launch_bounds__(256)
void gemm_mfma(const u16* __restrict__ fullH, const u16* __restrict__ fullL,
               const u16* __restrict__ relH,  const u16* __restrict__ relL,
               const u16* __restrict__ WqTH,  const u16* __restrict__ WqTL,
               const u16* __restrict__ WkvTH, const u16* __restrict__ WkvTL,
               const u16* __restrict__ WrTH,  const u16* __restrict__ WrTL,
               const u16* __restrict__ atH,   const u16* __restrict__ atL,
               const u16* __restrict__ WoTH,  const u16* __restrict__ WoTL,
               const float* __restrict__ bias_c,
               float* __restrict__ qc, u16* __restrict__ kb16, u16* __restrict__ vb16,
               u16* __restrict__ rb16, float* __restrict__ outp)
{
    extern __shared__ char lds[];   // main: 49152 B (2 x 24K); mode4: 65536 B (2 x 32K)
    constexpr int BSTR = (TNT == 8) ? 32768 : 24576;     // per-buffer stride

    int bid = blockIdx.x;
    int mode, m0, n0, arow0, npass;
    int kt0 = 0;                     // starting K-tile (split-K offset)
    const u16 *aH, *aL, *bH, *bL;
    if (TNT == 8) {
        // split-K x4: 512 blocks; sk = K-slice, local = (m,n) tile
        const int sk = bid >> 7;
        const int local = bid & 127;
        const int x = local & 7, g = local >> 3;         // g in [0,16)
        m0 = ((x >> 1) * 4 + (g >> 2)) * 128;
        n0 = ((x & 1) * 4 + (g & 3)) * 128;
        mode = 4; aH = atH; aL = atL; bH = WoTH; bL = WoTL; arow0 = m0; npass = 3;
        kt0 = sk * 8;
        outp += (size_t)sk * (2048u * 1024u);            // fp32 partial buffer
    } else if (bid < 128) {
        const int x = bid & 7, g = bid >> 3;             // g in [0,16)
        m0 = ((x >> 1) * 4 + (g >> 2)) * 128;
        n0 = ((x & 1) * 4 + (g & 3)) * 128;
        mode = 1; aH = fullH; aL = fullL; bH = WqTH; bL = WqTL;
        arow0 = (m0 >> 10) * cK + cM + (m0 & (cQ - 1)); npass = 2;
    } else if (bid < 640) {
        const int local = bid - 128;
        const int x = local & 7, g = local >> 3;         // g in [0,64)
        m0 = ((x >> 1) * 8 + (g >> 3)) * 128;
        n0 = ((x & 1) * 8 + (g & 7)) * 128;
        mode = 2; aH = fullH; aL = fullL; bH = WkvTH; bL = WkvTL; arow0 = m0;
        npass = (n0 >= cU) ? 1 : 2;
    } else {
        const int local = bid - 640;
        const int x = local & 7, g = local >> 3;         // g in [0,32)
        m0 = ((x >> 1) * 8 + (g >> 2)) * 128;
        n0 = ((x & 1) * 4 + (g & 3)) * 128;
        mode = 3; aH = relH; aL = relL; bH = WrTH; bL = WrTL; arow0 = m0; npass = 2;
    }

    const int t = threadIdx.x, w = t >> 6, lane = t & 63;

    const int rl = lane >> 2;
    const int cl = (lane & 3) ^ ((lane >> 3) & 3);  // XOR-swizzled chunk
    const u16* src;
    if (w == 0)      src = aH + (size_t)(arow0 + rl) * 1024 + cl * 8;
    else if (w == 1) src = aL + (size_t)(arow0 + rl) * 1024 + cl * 8;
    else if (w == 2) src = bH + (size_t)(n0 + rl) * 1024 + cl * 8;
    else             src = bL + (size_t)(n0 + rl) * 1024 + cl * 8;
    src += (size_t)kt0 * 32;                             // K-slice offset
    const int planeOff = w * 8192;
    const bool doStage = (w == 0) || (w == 2) || (w == 1 && npass >= 2) || (w == 3 && npass >= 3);

    // stage K-tile k (relative to kt0) into buffer buf
    auto stage = [&](int k, int buf) {
        if (doStage) {
            const u16* s = src + (size_t)k * 32;
            char* dst = lds + buf * BSTR + planeOff;
            #pragma unroll
            for (int g2 = 0; g2 < 8; ++g2)
                __builtin_amdgcn_global_load_lds((gp1)(s + (size_t)g2 * 16 * 1024),
                                                 (lp3)(dst + g2 * 1024), 16, 0, 0);
        }
    };

    const int l31 = lane & 31, hk = lane >> 5;
    const int fsw = (l31 >> 1) & 3;
    const int koff[2] = { ((hk ^ fsw) << 4), (((2 + hk) ^ fsw) << 4) };
    const int mwb = (w >> 1) * 4096 + l31 * 64;
    const int nwb = (w & 1) * 4096 + l31 * 64;

    v16f acc[2][2];
    #pragma unroll
    for (int i = 0; i < 16; ++i) { acc[0][0][i] = 0.f; acc[0][1][i] = 0.f; acc[1][0][i] = 0.f; acc[1][1][i] = 0.f; }

    // ---- prologue: tiles 0 and 1 in flight; wait only for tile 0 ----
    stage(0, 0);
    stage(1, 1);
    asm volatile("s_waitcnt vmcnt(8)" ::: "memory");
    __builtin_amdgcn_s_barrier();
    asm volatile("" ::: "memory");

    for (int kit = 0; kit < TNT; ++kit) {
        const char* ldsb = lds + ((kit & 1) ? BSTR : 0);

        #pragma unroll
        for (int s = 0; s < 2; ++s) {
            const int ko = koff[s];
            const v8bf ah0 = *(const v8bf*)(ldsb + mwb + ko);
            const v8bf ah1 = *(const v8bf*)(ldsb + mwb + 2048 + ko);
            const v8bf bh0 = *(const v8bf*)(ldsb + 16384 + nwb + ko);
            const v8bf bh1 = *(const v8bf*)(ldsb + 16384 + nwb + 2048 + ko);
            acc[0][0] = MFMA32(ah0, bh0, acc[0][0]);
            acc[0][1] = MFMA32(ah0, bh1, acc[0][1]);
            acc[1][0] = MFMA32(ah1, bh0, acc[1][0]);
            acc[1][1] = MFMA32(ah1, bh1, acc[1][1]);
            if (npass >= 2) {
                const v8bf al0 = *(const v8bf*)(ldsb + 8192 + mwb + ko);
                const v8bf al1 = *(const v8bf*)(ldsb + 8192 + mwb + 2048 + ko);
                acc[0][0] = MFMA32(al0, bh0, acc[0][0]);
                acc[0][1] = MFMA32(al0, bh1, acc[0][1]);
                acc[1][0] = MFMA32(al1, bh0, acc[1][0]);
                acc[1][1] = MFMA32(al1, bh1, acc[1][1]);
            }
            if (npass >= 3) {
                const v8bf bl0 = *(const v8bf*)(ldsb + 24576 + nwb + ko);
                const v8bf bl1 = *(const v8bf*)(ldsb + 24576 + nwb + 2048 + ko);
                acc[0][0] = MFMA32(ah0, bl0, acc[0][0]);
                acc[0][1] = MFMA32(ah0, bl1, acc[0][1]);
                acc[1][0] = MFMA32(ah1, bl0, acc[1][0]);
                acc[1][1] = MFMA32(ah1, bl1, acc[1][1]);
            }
        }

        if (kit == TNT - 1) break;

        // A: all waves done reading buf[kit&1]
        asm volatile("" ::: "memory");
        __builtin_amdgcn_s_barrier();
        asm volatile("" ::: "memory");

        if (kit <= TNT - 3) {
            stage(kit + 2, kit & 1);                       // overwrite freed buffer
            asm volatile("s_waitcnt vmcnt(8)" ::: "memory"); // tile kit+1 landed
        } else {
            asm volatile("s_waitcnt vmcnt(0)" ::: "memory"); // drain last tile
        }

        // B: publish buf[(kit+1)&1]
        __builtin_amdgcn_s_barrier();
        asm volatile("" ::: "memory");
    }

    #pragma unroll
    for (int mi = 0; mi < 2; ++mi)
    #pragma unroll
    for (int ni = 0; ni < 2; ++ni) {
        const int n = n0 + (w & 1) * 64 + ni * 32 + l31;
        #pragma unroll
        for (int e = 0; e < 16; ++e) {
            const int m = m0 + (w >> 1) * 64 + mi * 32 + (e & 3) + 8 * (e >> 2) + 4 * hk;
            const float v = acc[mi][ni][e];
            if (mode == 1) {
                const int b = m >> 10, q = m & (cQ - 1);
                const int h = n >> 6, d = n & 63;
                qc[(((size_t)(b * cH + h)) * cQ + q) * cD + d] = v + bias_c[n];
            } else if (mode == 2) {
                const int b = m >> 11, l = m & (cK - 1);
                const int nn = n & (cU - 1);
                const int h = nn >> 6, d = nn & 63;
                if (n >= cU)   // V fragment-linear
                    vb16[(size_t)(b * cH + h) * cK * cD + ((l >> 6) * 4096)
                         + (((l >> 4) & 3) * 1024) + (((l >> 3) & 1) * 512)
                         + d * 8 + (l & 7)] = f2bf(v);
                else           // K fragment-linear
                    kb16[(size_t)(b * cH + h) * cK * cD + ((l >> 6) * 4096)
                         + ((d >> 4) * 1024) + (((d >> 3) & 1) * 512)
                         + ((l & 63) * 8) + (d & 7)] = f2bf(v);
            } else if (mode == 3) {
                const int b = m >> 11, l = m & (cK - 1);
                const int h = n >> 6, d = n & 63;
                rb16[(size_t)(b * cH + h) * cRROWS * cD + ((l >> 5) * 2048)
                     + ((d >> 4) * 512) + (((d >> 3) & 1) * 256)
                     + ((l & 31) * 8) + (d & 7)] = f2bf(v);
            } else {
                outp[(size_t)m * cU + n] = v;              // fp32 partial
            }
        }
    }
}

// ---------------------------------------------------------------------------
// add4: out = p0 + p1 + p2 + p3 (split-K reduction for the out-projection)
// ---------------------------------------------------------------------------
__global__ __launch_bounds__(256)
void add4(const float* __restrict__ part, float* __restrict__ out)
{
    const size_t base = ((size_t)blockIdx.x * 256 + threadIdx.x) * 4;
    constexpr size_t S = 2048u * 1024u;
    const float4 a = *(const float4*)(part + base);
    const float4 b = *(const float4*)(part + S + base);
    const float4 c = *(const float4*)(part + 2 * S + base);
    const float4 d = *(const float4*)(part + 3 * S + base);
    float4 r;
    r.x = (a.x + b.x) + (c.x + d.x);
    r.y = (a.y + b.y) + (c.y + d.y);
    r.z = (a.z + b.z) + (c.z + d.z);
    r.w = (a.w + b.w) + (c.w + d.w);
    *(float4*)(out + base) = r;
}

// ---------------------------------------------------------------------------
// wvec: w_all[bh][win] = sum_d r[bh][win][d] * (bias_r - bias_c)[h][d]
// ---------------------------------------------------------------------------
__global__ __launch_bounds__(256)
void wvec_kernel(const u16* __restrict__ rb16, const float* __restrict__ bias_c,
                 const float* __restrict__ bias_r, float* __restrict__ w_all)
{
    const int t = threadIdx.x, w = t >> 6, lane = t & 63;
    #pragma unroll 4
    for (int it = 0; it < 16; ++it) {
        const int row = blockIdx.x * 64 + it * 4 + w;    // 65536 rows
        const int bh = row >> 11, g = row & (cK - 1);
        const int h = bh & (cH - 1);
        const float d = bias_r[h * 64 + lane] - bias_c[h * 64 + lane];
        const size_t idx = (size_t)bh * cRROWS * cD + ((g >> 5) * 2048)
                         + ((lane >> 4) * 512) + (((lane >> 3) & 1) * 256)
                         + ((g & 31) * 8) + (lane & 7);
        float v = bf2f(rb16[idx]) * d;
        #pragma unroll
        for (int off = 1; off <= 32; off <<= 1)
            v += __shfl_xor(v, off);
        if (lane == 0) w_all[(size_t)bh * cWPAD + g] = v;
    }
}

// ---------------------------------------------------------------------------
// MFMA flash attention — round-7 proven structure + hardware bf16 converts
// in the two hot VALU paths (SrelT pack, Ph store). Profile r13: VALUBusy
// 45% / MfmaUtil 12% -> VALU chain is the critical path; the 3-op integer
// RTNE f2bf is replaced by native casts so ISel emits v_cvt_pk_bf16_f32
// (~70 of ~250 VALU ops/chunk removed). RTNE == RTNE: bit-identical.
// ---------------------------------------------------------------------------
__global__ __launch_bounds__(256, 4)
void flash_mfma(const float* __restrict__ qcg, const u16* __restrict__ kbg,
                const u16* __restrict__ vbg, const u16* __restrict__ rbg,
                const float* __restrict__ w_all,
                float* __restrict__ oPart, float* __restrict__ lPart)
{
    __shared__ u16 KhL[4096];        // fragment-linear K chunk (8 KB)
    __shared__ u16 RhL[8192];        // fragment-linear R window (16 KB)
    __shared__ u16 SrelT[128][68];   // [window][q-row] bf16 (wv folded)
    __shared__ u16 Ph[64][68];       // [q-row][key] bf16
    __shared__ float lrow[2][64];

    const int bid = blockIdx.x;
    const int hb = bid & 31;
    const int inner = bid >> 5;
    const int qb = inner & 15;
    const int sp = inner >> 4;         // split 0/1
    const int h = hb >> 1, b = hb & 1;
    const int bh = b * cH + h;
    const int q0 = qb * 64;

    const u16* kgf = kbg + (size_t)bh * cK * cD;
    const u16* vgf = vbg + (size_t)bh * cK * cD;
    const u16* rgf = rbg + (size_t)bh * cRROWS * cD;
    const float* qg = qcg + (size_t)bh * cQ * cD;
    const float* wg = w_all + (size_t)bh * cWPAD;

    const int t = threadIdx.x, w = t >> 6, lane = t & 63;
    const int l31 = lane & 31, hk = lane >> 5;
    const int rloc0 = (w >> 1) * 32;
    const int c0 = (w & 1) * 32;
    const int wc0 = (w & 1) * 64 + l31;

    Frag qch[4];
    {
        const float* qrow = qg + (size_t)(q0 + rloc0 + l31) * cD;
        #pragma unroll
        for (int kc = 0; kc < 4; ++kc) {
            const int dh0 = kc * 16 + hk * 8;
            const float4 f0 = *(const float4*)(qrow + dh0);
            const float4 f1 = *(const float4*)(qrow + dh0 + 4);
            const float xs[8] = {f0.x, f0.y, f0.z, f0.w, f1.x, f1.y, f1.z, f1.w};
            #pragma unroll
            for (int j = 0; j < 8; ++j) qch[kc].s[j] = f2bf(xs[j]);
        }
    }

    v16f aO;
    float lpart[16];
    #pragma unroll
    for (int i = 0; i < 16; ++i) { aO[i] = 0.f; lpart[i] = 0.f; }

    const int nch = 17 + qb;
    int j0 = sp * 64;

    auto dma = [&](int jn, int relbn) {
        #pragma unroll
        for (int i = 0; i < 6; ++i) {
            const int id = w * 6 + i;
            if (id < 8) {
                const u16* s = kgf + (size_t)(jn >> 6) * 4096 + id * 512;
                __builtin_amdgcn_global_load_lds((gp1)(s + lane * 8),
                                                 (lp3)((char*)KhL + id * 1024), 16, 0, 0);
            } else {
                const int jj = id - 8;
                const u16* s = rgf + ((size_t)(relbn >> 5) + (jj >> 2)) * 2048 + (jj & 3) * 512;
                __builtin_amdgcn_global_load_lds((gp1)(s + lane * 8),
                                                 (lp3)((char*)RhL + jj * 1024), 16, 0, 0);
            }
        }
    };

    dma(j0, j0 - q0 + 960);
    __syncthreads();

    for (int c = sp; c < nch; c += 2) {
        const int relbase = j0 - q0 + 960;

        Frag vf[4];
        #pragma unroll
        for (int kc = 0; kc < 4; ++kc)
            vf[kc].q4 = *(const uint4*)(vgf + (size_t)(j0 >> 6) * 4096
                                        + kc * 1024 + hk * 512 + (c0 + l31) * 8);
        const float wv0 = wg[relbase + wc0];
        const float wv1 = wg[relbase + wc0 + 32];

        v16f actx;
        #pragma unroll
        for (int i = 0; i < 16; ++i) actx[i] = 0.f;
        #pragma unroll
        for (int kc = 0; kc < 4; ++kc) {
            Frag kf;
            kf.q4 = *(const uint4*)(KhL + kc * 1024 + hk * 512 + (c0 + l31) * 8);
            actx = MFMA32(qch[kc].v, kf.v, actx);
        }

        #pragma unroll
        for (int half = 0; half < 2; ++half) {
            v16f ar;
            #pragma unroll
            for (int i = 0; i < 16; ++i) ar[i] = 0.f;
            const int lg = (w & 1) * 2 + half;
            #pragma unroll
            for (int kc = 0; kc < 4; ++kc) {
                Frag rf;
                rf.q4 = *(const uint4*)(RhL + lg * 2048 + kc * 512 + hk * 256 + l31 * 8);
                ar = MFMA32(qch[kc].v, rf.v, ar);
            }
            const float wvh = half ? wv1 : wv0;
            const int wch = wc0 + half * 32;
            #pragma unroll
            for (int g = 0; g < 4; ++g) {
                const int rb_ = rloc0 + 8 * g + 4 * hk;
                u16 p[4];
                #pragma unroll
                for (int e = 0; e < 4; ++e) p[e] = f2bf_hw(ar[4 * g + e] + wvh);
                *(uint2*)&SrelT[wch][rb_] = make_uint2(p[0] | ((u32)p[1] << 16),
                                                       p[2] | ((u32)p[3] << 16));
            }
        }
        __syncthreads();   // B: SrelT visible; KhL/RhL fully consumed

        const int jn = (c + 2 < nch) ? j0 + 128 : j0;
        dma(jn, jn - q0 + 960);

        const int jl = c0 + l31;
        const int limit = cM + q0 - j0;
        #pragma unroll
        for (int g = 0; g < 4; ++g)
        #pragma unroll
        for (int e = 0; e < 4; ++e) {
            const int reg  = 4 * g + e;
            const int rloc = rloc0 + e + 8 * g + 4 * hk;
            const int widx = jl - rloc + 63;            // [0,126]
            const float srel = bf2f(SrelT[widx][rloc]);
            const float s = (actx[reg] + srel) * 0.125f - 10.f;
            const float p = (jl > limit + rloc) ? 0.f : __expf(s);
            lpart[reg] += p;
            Ph[rloc][jl] = f2bf_hw(p);
        }
        __syncthreads();   // C: Ph visible; DMA drained

        #pragma unroll
        for (int kc = 0; kc < 4; ++kc) {
            const int kb0 = kc * 16 + hk * 8;
            Frag pf;
            pf.d2[0] = *(const uint2*)&Ph[rloc0 + l31][kb0];
            pf.d2[1] = *(const uint2*)&Ph[rloc0 + l31][kb0 + 4];
            aO = MFMA32(pf.v, vf[kc].v, aO);
        }
        j0 += 128;
    }

    #pragma unroll
    for (int off = 1; off <= 16; off <<= 1)
        #pragma unroll
        for (int i = 0; i < 16; ++i) lpart[i] += __shfl_xor(lpart[i], off);
    if (l31 == 0) {
        #pragma unroll
        for (int g = 0; g < 4; ++g)
        #pragma unroll
        for (int e = 0; e < 4; ++e)
            lrow[w & 1][rloc0 + e + 8 * g + 4 * hk] = lpart[4 * g + e];
    }
    __syncthreads();

    float* ob = oPart + (size_t)sp * ((size_t)cB * cQ * cU);
    #pragma unroll
    for (int g = 0; g < 4; ++g)
    #pragma unroll
    for (int e = 0; e < 4; ++e) {
        const int reg  = 4 * g + e;
        const int rloc = rloc0 + e + 8 * g + 4 * hk;
        ob[((size_t)(b * cQ + q0 + rloc)) * cU + h * 64 + c0 + l31] = aO[reg];
    }
    if (t < 64)
        lPart[(size_t)sp * (cB * cH * cQ) + (size_t)bh * cQ + q0 + t] = lrow[0][t] + lrow[1][t];
}

// ---------------------------------------------------------------------------
// combine: o = (o0+o1)/(l0+l1), write bf16 hi/lo for the out-GEMM.
// ---------------------------------------------------------------------------
__global__ __launch_bounds__(256)
void combine(const float* __restrict__ oPart, const float* __restrict__ lPart,
             u16* __restrict__ atH, u16* __restrict__ atL)
{
    const int idx = blockIdx.x * 256 + threadIdx.x;
    const size_t base = (size_t)idx * 4;
    const int b = (int)(base >> 20);
    const int rem = (int)(base & ((1u << 20) - 1));
    const int q = rem >> 10;
    const int u = rem & 1023;
    const int h = u >> 6;
    const float4 o0 = *(const float4*)(oPart + base);
    const float4 o1 = *(const float4*)(oPart + (size_t)cB * cQ * cU + base);
    const int li = (b * cH + h) * cQ + q;
    const float l = lPart[li] + lPart[cB * cH * cQ + li];
    const float inv = 1.f / l;
    const float vals[4] = {(o0.x + o1.x) * inv, (o0.y + o1.y) * inv,
                           (o0.z + o1.z) * inv, (o0.w + o1.w) * inv};
    u16 hi[4], lo[4];
    #pragma unroll
    for (int j = 0; j < 4; ++j) {
        hi[j] = f2bf(vals[j]);
        lo[j] = f2bf(vals[j] - bf2f(hi[j]));
    }
    uint2 ph, pl;
    ph.x = hi[0] | ((u32)hi[1] << 16); ph.y = hi[2] | ((u32)hi[3] << 16);
    pl.x = lo[0] | ((u32)lo[1] << 16); pl.y = lo[2] | ((u32)lo[3] << 16);
    *(uint2*)(atH + base) = ph;
    *(uint2*)(atL + base) = pl;
}

// ---------------------------------------------------------------------------
extern "C" void kernel_launch(void* const* d_in, const int* in_sizes, int n_in,
                              void* d_out, int out_size, void* d_ws, size_t ws_size,
                              hipStream_t stream)
{
    const float* inputs    = (const float*)d_in[0];
    const float* relatives = (const float*)d_in[1];
    const float* memories  = (const float*)d_in[2];
    const float* bias_c    = (const float*)d_in[3];
    const float* bias_r    = (const float*)d_in[4];
    const float* Wq        = (const float*)d_in[5];
    const float* Wkv       = (const float*)d_in[6];
    const float* Wr        = (const float*)d_in[7];
    const float* Wo        = (const float*)d_in[8];
    float* out = (float*)d_out;

    char* p = (char*)d_ws;
    auto alloc = [&](size_t bytes) { char* r = p; p += bytes; return r; };
    u16* fullH = (u16*)alloc(8u << 20);
    u16* fullL = (u16*)alloc(8u << 20);
    u16* relH  = (u16*)alloc(8u << 20);   // oPart aliases relH+relL after proj
    u16* relL  = (u16*)alloc(8u << 20);
    u16* WqTH  = (u16*)alloc(2u << 20);
    u16* WqTL  = (u16*)alloc(2u << 20);
    u16* WkvTH = (u16*)alloc(4u << 20);
    u16* WkvTL = (u16*)alloc(4u << 20);
    u16* WrTH  = (u16*)alloc(2u << 20);
    u16* WrTL  = (u16*)alloc(2u << 20);
    u16* WoTH  = (u16*)alloc(2u << 20);
    u16* WoTL  = (u16*)alloc(2u << 20);
    float* qc  = (float*)alloc(8u << 20);
    u16* kb16  = (u16*)alloc(8u << 20);
    u16* vb16  = (u16*)alloc(8u << 20);
    u16* rb16  = (u16*)alloc(9u << 20);   // 32 bh x 2112 rows x 64 (fragment-linear)
    float* w_all = (float*)alloc(32u * cWPAD * 4u);
    float* lPart = (float*)alloc(2u * cB * cH * cQ * 4u);
    u16* atH   = (u16*)alloc(4u << 20);
    u16* atL   = (u16*)alloc(4u << 20);
    float* oPart = (float*)relH;          // 16 MB, reuses rel planes
    float* part4 = (float*)d_ws;          // 32 MB overlay (fullH..relL), free
                                          // after combine; holds split-K partials

    convert_fused<<<9472, 256, 0, stream>>>(inputs, memories, relatives,
                                            fullH, fullL, relH, relL,
                                            Wq, Wkv, Wr, Wo,
                                            WqTH, WqTL, WkvTH, WkvTL,
                                            WrTH, WrTL, WoTH, WoTL);
    gemm_mfma<32><<<896, 256, 49152, stream>>>(fullH, fullL, relH, relL,
                                               WqTH, WqTL, WkvTH, WkvTL, WrTH, WrTL,
                                               atH, atL, WoTH, WoTL, bias_c,
                                               qc, kb16, vb16, rb16, out);
    wvec_kernel<<<1024, 256, 0, stream>>>(rb16, bias_c, bias_r, w_all);
    flash_mfma<<<1024, 256, 0, stream>>>(qc, kb16, vb16, rb16, w_all, oPart, lPart);
    combine<<<2048, 256, 0, stream>>>(oPart, lPart, atH, atL);
    gemm_mfma<8><<<512, 256, 65536, stream>>>(fullH, fullL, relH, relL,
                                              WqTH, WqTL, WkvTH, WkvTL, WrTH, WrTL,
                                              atH, atL, WoTH, WoTL, bias_c,
                                              qc, kb16, vb16, rb16, part4);
    add4<<<2048, 256, 0, stream>>>(part4, out);
}